// Round 4
// baseline (217.839 us; speedup 1.0000x reference)
//
#include <hip/hip_runtime.h>
#include <hip/hip_bf16.h>

#define N_NODES 100000
#define D_FEAT 64
#define CAP 64          // slots per dst node; in-deg ~ 1+Poisson(16), P(>63) ~ 1e-14
#define NB 392          // coarse buckets of 256 nodes: 392*256 = 100352 >= n+1
#define CB_CAP 5500     // per-bucket record capacity (mean 4352, +17 sigma)
#define PT 512          // partition threads per block
#define EPT 7           // edges register-cached per thread; chunk = EPT*PT = 3584

typedef unsigned int uint;
typedef unsigned short ushort;

// fp32 -> bf16 round-to-nearest-even
__device__ __forceinline__ uint f2bf(float f) {
    uint u = __float_as_uint(f);
    return (u + 0x7fffu + ((u >> 16) & 1u)) >> 16;
}

// ========== pass 1: coarse partition of edges by dst>>8 + deg_out atomics ==
// Single-read: each thread caches its <=EPT edges in registers (statically
// indexed under full unroll), histograms dst-buckets from registers, reserves
// one contiguous run per (block,bucket), then replays from registers.
// deg_out is built here with NO-RETURN global atomics spread over 100K
// addresses (~17/addr, low contention -- unlike round 2's with-return
// atomics on 512 hot addresses).  The entire srcrec side-channel is gone.
__global__ __launch_bounds__(PT) void
partition_kernel(const int* __restrict__ src, const int* __restrict__ dst,
                 int* __restrict__ deg_out, int* __restrict__ dstCur,
                 uint* __restrict__ dstrec, int nE) {
    __shared__ int hd[NB], bd[NB];
    const int t = threadIdx.x;
    for (int i = t; i < NB; i += PT) hd[i] = 0;
    __syncthreads();
    const int beg = blockIdx.x * (EPT * PT);
    int se[EPT], de[EPT];
#pragma unroll
    for (int k = 0; k < EPT; ++k) {
        int e = beg + t + k * PT;
        int s = 0, d = 0;
        if (e < nE) { s = src[e]; d = dst[e]; }   // coalesced
        se[k] = s; de[k] = d;
        if (e < nE) {
            atomicAdd(&hd[d >> 8], 1);            // LDS, bucket histogram
            atomicAdd(&deg_out[s], 1);            // global, fire-and-forget
        }
    }
    __syncthreads();
    for (int i = t; i < NB; i += PT) {
        bd[i] = atomicAdd(&dstCur[i], hd[i]);
        hd[i] = 0;
    }
    __syncthreads();
#pragma unroll
    for (int k = 0; k < EPT; ++k) {
        int e = beg + t + k * PT;
        if (e < nE) {
            int d = de[k], s = se[k];
            int b = d >> 8;
            int p = bd[b] + atomicAdd(&hd[b], 1);
            if (p < CB_CAP)
                dstrec[(size_t)b * CB_CAP + p] = ((uint)(d & 255) << 17) | (uint)s;  // s < 2^17
        }
    }
}

// ========== pass 2: fused bin + prescale ===================================
// Blocks 0..NB-1: fine-bin dst records -> edge_src + cursor via per-bucket
//   LDS cursors (block-local atomics; round 2 proved global atomic-with-
//   return cursors are 2x worse).  256-node buckets -> 784 total blocks
//   (~3/CU) for load balance vs round 3's 196 heavy blocks.
// Blocks NB..2NB-1: prescale -- read global deg_out directly (1KB/block),
//   emit xb[row] = bf16(rsqrt(deg_out)*feat[row]); pad row n = zeros.
__global__ __launch_bounds__(256) void
bin_kernel(const uint* __restrict__ dstrec, const int* __restrict__ dstCur,
           const int* __restrict__ deg_out,
           int* __restrict__ cursor, int* __restrict__ edge_src,
           const float* __restrict__ feat, uint2* __restrict__ xb, int n) {
    __shared__ int lc[256];
    const int t = threadIdx.x;
    if ((int)blockIdx.x < NB) {
        const int b = blockIdx.x;
        const int base = b << 8;
        const int nNodes = min(256, n - base);        // <=0 for bucket 391
        for (int i = t; i < 256; i += 256) lc[i] = 0;
        __syncthreads();
        int cnt = min(dstCur[b], CB_CAP);
        const uint* rec = dstrec + (size_t)b * CB_CAP;
#pragma unroll 4
        for (int i = t; i < cnt; i += 256) {
            uint r = rec[i];
            int dl = r >> 17;
            int s  = r & 0x1FFFF;
            int p = atomicAdd(&lc[dl], 1);
            if (p < CAP) edge_src[(size_t)(base + dl) * CAP + p] = s;  // 64 KB window, L2-local
        }
        __syncthreads();
        for (int i = t; i < nNodes; i += 256) cursor[base + i] = lc[i];
    } else {
        const int b = blockIdx.x - NB;
        const int base = b << 8;
        const int rows = min(256, n + 1 - base);      // includes pad row n; <=0 past it
        const int d4 = t & 15;
        for (int r = t >> 4; r < rows; r += 16) {     // 16 rows/iter, coalesced
            const int row = base + r;
            uint2 o;
            if (row == n) {
                o.x = 0u; o.y = 0u;
            } else {
                float w = rsqrtf((float)max(deg_out[row], 1));
                float4 v = ((const float4*)feat)[(size_t)row * 16 + d4];
                o.x = f2bf(w * v.x) | (f2bf(w * v.y) << 16);
                o.y = f2bf(w * v.z) | (f2bf(w * v.w) << 16);
            }
            xb[(size_t)row * 16 + d4] = o;
        }
    }
}

// ========== pass 3: gather (body 32 / tail 16 / tail 8) ====================
// One wave per dst row; WAVE-UNIFORM loop (shfl source lanes must stay active).
// Pads read the zero row -> numerics identical.
__global__ __launch_bounds__(256) void
gather_bf16_kernel(const uint2* __restrict__ xb,
                   const int* __restrict__ edge_src,
                   const int* __restrict__ cursor,
                   float* __restrict__ out, int n) {
    int wave = (blockIdx.x * blockDim.x + threadIdx.x) >> 6;
    if (wave >= n) return;
    int lane = threadIdx.x & 63;
    int cnt = min(cursor[wave], CAP);                  // wave-uniform

    int s_l = (lane < cnt) ? edge_src[(size_t)wave * CAP + lane] : n;

    int sub = lane >> 4;
    int d4  = lane & 15;
    float4 acc = {0.f, 0.f, 0.f, 0.f};

    const int rounded = (cnt + 7) & ~7;
    int i = 0;
    for (; i + 32 <= rounded; i += 32) {               // 8-load MLP body
        int   s[8];
        uint2 v[8];
#pragma unroll
        for (int k = 0; k < 8; ++k)
            s[k] = __shfl(s_l, i + sub + 4 * k, 64);   // max index 32+3+28 = 63
#pragma unroll
        for (int k = 0; k < 8; ++k)
            v[k] = xb[(size_t)s[k] * 16 + d4];
#pragma unroll
        for (int k = 0; k < 8; ++k) {
            acc.x += __uint_as_float(v[k].x << 16);
            acc.y += __uint_as_float(v[k].x & 0xffff0000u);
            acc.z += __uint_as_float(v[k].y << 16);
            acc.w += __uint_as_float(v[k].y & 0xffff0000u);
        }
    }
    if (i + 16 <= rounded) {                           // 16-slot tail
        int   s[4];
        uint2 v[4];
#pragma unroll
        for (int k = 0; k < 4; ++k)
            s[k] = __shfl(s_l, i + sub + 4 * k, 64);
#pragma unroll
        for (int k = 0; k < 4; ++k)
            v[k] = xb[(size_t)s[k] * 16 + d4];
#pragma unroll
        for (int k = 0; k < 4; ++k) {
            acc.x += __uint_as_float(v[k].x << 16);
            acc.y += __uint_as_float(v[k].x & 0xffff0000u);
            acc.z += __uint_as_float(v[k].y << 16);
            acc.w += __uint_as_float(v[k].y & 0xffff0000u);
        }
        i += 16;
    }
    if (i < rounded) {                                 // 8-slot tail
        int   s[2];
        uint2 v[2];
#pragma unroll
        for (int k = 0; k < 2; ++k)
            s[k] = __shfl(s_l, i + sub + 4 * k, 64);
#pragma unroll
        for (int k = 0; k < 2; ++k)
            v[k] = xb[(size_t)s[k] * 16 + d4];
#pragma unroll
        for (int k = 0; k < 2; ++k) {
            acc.x += __uint_as_float(v[k].x << 16);
            acc.y += __uint_as_float(v[k].x & 0xffff0000u);
            acc.z += __uint_as_float(v[k].y << 16);
            acc.w += __uint_as_float(v[k].y & 0xffff0000u);
        }
    }
    for (int off = 16; off < 64; off <<= 1) {
        acc.x += __shfl_xor(acc.x, off, 64);
        acc.y += __shfl_xor(acc.y, off, 64);
        acc.z += __shfl_xor(acc.z, off, 64);
        acc.w += __shfl_xor(acc.w, off, 64);
    }
    if (sub == 0) {
        float si = rsqrtf((float)max(cnt, 1));         // rs_in
        float4 r = { acc.x * si, acc.y * si, acc.z * si, acc.w * si };
        ((float4*)out)[(size_t)wave * 16 + d4] = r;
    }
}

// ========== fallback: R8's proven single-pass fp32 path ====================
__global__ void bucket_kernel(const int* __restrict__ src, const int* __restrict__ dst,
                              int* __restrict__ cursor, int* __restrict__ deg_out,
                              int* __restrict__ edge_src, int nE) {
    int e = blockIdx.x * blockDim.x + threadIdx.x;
    if (e < nE) {
        int s = src[e];
        int d = dst[e];
        atomicAdd(&deg_out[s], 1);
        int pos = atomicAdd(&cursor[d], 1);
        if (pos < CAP) edge_src[(size_t)d * CAP + pos] = s;
    }
}

__global__ void gather_cap_kernel(const float* __restrict__ feat,
                                  const int* __restrict__ edge_src,
                                  const int* __restrict__ cursor,
                                  const int* __restrict__ deg_out,
                                  float* __restrict__ out, int n) {
    int wave = (blockIdx.x * blockDim.x + threadIdx.x) >> 6;
    if (wave >= n) return;
    int lane = threadIdx.x & 63;
    int cnt = min(cursor[wave], CAP);

    int   s_l = (lane < cnt) ? edge_src[(size_t)wave * CAP + lane] : 0;
    float w_l = (lane < cnt) ? rsqrtf((float)max(deg_out[s_l], 1)) : 0.0f;

    int sub = lane >> 4;
    int d4  = lane & 15;
    float4 a0 = {0.f,0.f,0.f,0.f}, a1 = {0.f,0.f,0.f,0.f};

    for (int i = 0; i < cnt; i += 8) {
        int   s0 = __shfl(s_l, i + sub, 64);
        float w0 = __shfl(w_l, i + sub, 64);
        int   s1 = __shfl(s_l, i + sub + 4, 64);
        float w1 = __shfl(w_l, i + sub + 4, 64);
        float4 v0 = ((const float4*)feat)[(size_t)s0 * 16 + d4];
        float4 v1 = ((const float4*)feat)[(size_t)s1 * 16 + d4];
        a0.x += w0 * v0.x; a0.y += w0 * v0.y; a0.z += w0 * v0.z; a0.w += w0 * v0.w;
        a1.x += w1 * v1.x; a1.y += w1 * v1.y; a1.z += w1 * v1.z; a1.w += w1 * v1.w;
    }
    float4 acc = { a0.x + a1.x, a0.y + a1.y, a0.z + a1.z, a0.w + a1.w };
    for (int off = 16; off < 64; off <<= 1) {
        acc.x += __shfl_xor(acc.x, off, 64);
        acc.y += __shfl_xor(acc.y, off, 64);
        acc.z += __shfl_xor(acc.z, off, 64);
        acc.w += __shfl_xor(acc.w, off, 64);
    }
    if (sub == 0) {
        float si = rsqrtf((float)max(cnt, 1));
        float4 r = { acc.x * si, acc.y * si, acc.z * si, acc.w * si };
        ((float4*)out)[(size_t)wave * 16 + d4] = r;
    }
}

// ===========================================================================

extern "C" void kernel_launch(void* const* d_in, const int* in_sizes, int n_in,
                              void* d_out, int out_size, void* d_ws, size_t ws_size,
                              hipStream_t stream) {
    const float* feat = (const float*)d_in[0];
    const int*   src  = (const int*)d_in[1];
    const int*   dst  = (const int*)d_in[2];
    float* out = (float*)d_out;
    const int nE = in_sizes[1];
    const int n  = N_NODES;

    // Fast-path layout (512-B aligned sections; xb rows must not straddle
    // cache lines -- round 1 proved a 96-mod-128 xb offset costs ~14 us):
    //   cursor[n] | deg_out[n] dstCur[NB] | dstrec | xb | edge_src
    // One memset covers deg_out..dstCur (contiguous).  cursor needs no init.
    const size_t cur_off   = 0;
    const size_t deg_off   = (size_t)n * sizeof(int);                 // 400,000
    const size_t ctr_off   = deg_off + (size_t)n * sizeof(int);       // dstCur right after deg_out
    const size_t rec_off   = (ctr_off + NB * sizeof(int) + 511) & ~(size_t)511;
    const size_t dstrec_sz = (size_t)NB * CB_CAP * sizeof(uint);      // 8,624,000
    const size_t xb_off    = (rec_off + dstrec_sz + 511) & ~(size_t)511;
    const size_t xb_bytes  = (size_t)(n + 1) * 16 * sizeof(uint2);    // 12,800,128
    const size_t es_off    = (xb_off + xb_bytes + 511) & ~(size_t)511;
    const size_t need_new  = es_off + (size_t)n * CAP * sizeof(int);
    const size_t need_fp   = (size_t)n * (2 + CAP) * sizeof(int);     // ~26.4 MB

    if (ws_size >= need_new) {
        char*   W        = (char*)d_ws;
        int*    cursor   = (int*)(W + cur_off);
        int*    deg_out  = (int*)(W + deg_off);
        int*    dstCur   = (int*)(W + ctr_off);
        uint*   dstrec   = (uint*)(W + rec_off);
        uint2*  xb       = (uint2*)(W + xb_off);
        int*    edge_src = (int*)(W + es_off);

        // deg_out (atomic targets) + dstCur need zeroing; cursor does not.
        hipMemsetAsync(deg_out, 0, (size_t)n * sizeof(int) + NB * sizeof(int), stream);
        {
            const int chunk = EPT * PT;                       // 3584
            const int grid = (nE + chunk - 1) / chunk;        // 475 for 1.7M edges
            partition_kernel<<<grid, PT, 0, stream>>>(src, dst, deg_out, dstCur,
                                                      dstrec, nE);
        }
        bin_kernel<<<2 * NB, 256, 0, stream>>>(dstrec, dstCur, deg_out,
                                               cursor, edge_src, feat, xb, n);
        {
            int grid = (n + 3) / 4;   // 4 waves = 4 rows per block
            gather_bf16_kernel<<<grid, 256, 0, stream>>>(xb, edge_src, cursor, out, n);
        }
    } else if (ws_size >= need_fp) {
        // R8's proven fp32 path: cursor[n] | deg_out[n] | edge_src[n*CAP]
        int* cursor   = (int*)d_ws;
        int* deg_out  = cursor + n;
        int* edge_src = deg_out + n;

        hipMemsetAsync(cursor, 0, 2 * (size_t)n * sizeof(int), stream);
        {
            int block = 256, grid = (nE + block - 1) / block;
            bucket_kernel<<<grid, block, 0, stream>>>(src, dst, cursor, deg_out, edge_src, nE);
        }
        {
            int block = 256, grid = (n + 3) / 4;
            gather_cap_kernel<<<grid, block, 0, stream>>>(feat, edge_src, cursor, deg_out, out, n);
        }
    }
}

// Round 5
// 164.161 us; speedup vs baseline: 1.3270x; 1.3270x over previous
//
#include <hip/hip_runtime.h>
#include <hip/hip_bf16.h>

#define N_NODES 100000
#define D_FEAT 64
#define CAP 64          // fallback path only
#define NBD 784         // dst buckets of 128 nodes: 784*128 = 100352 >= n
#define DB_CAP 3072     // per-dst-bucket record cap (mean 2176, +19 sigma) == LDS CSR cap
#define NBS 392         // src buckets of 256 nodes: 392*256 = 100352 >= n+1
#define SB_CAP 5500     // per-src-bucket record cap (mean 4336, +17 sigma)
#define PT 512          // partition threads per block
#define EPT 7           // edges register-cached per thread; chunk = EPT*PT = 3584

typedef unsigned int uint;
typedef unsigned short ushort;

// fp32 -> bf16 round-to-nearest-even
__device__ __forceinline__ uint f2bf(float f) {
    uint u = __float_as_uint(f);
    return (u + 0x7fffu + ((u >> 16) & 1u)) >> 16;
}

// ========== pass 1: coarse partition (dst>>7 records, src>>8 records) ======
// Single-read: each thread caches its <=EPT edges in registers (statically
// indexed under full unroll), LDS-histograms both keys, reserves contiguous
// runs with ONE global atomic per (block,bucket), replays from registers.
// ALL per-edge atomics are LDS: round 2 (with-return, hot lines) and round 4
// (no-return, scattered deg_out) both proved per-edge GLOBAL atomics are
// 2x-worse memory-side RMWs.
__global__ __launch_bounds__(PT) void
partition_kernel(const int* __restrict__ src, const int* __restrict__ dst,
                 int* __restrict__ dstCur, int* __restrict__ srcCur,
                 uint* __restrict__ dstrec, ushort* __restrict__ srcrec,
                 int nE) {
    __shared__ int hd[NBD], bd[NBD], hs[NBS], bs[NBS];
    const int t = threadIdx.x;
    for (int i = t; i < NBD; i += PT) hd[i] = 0;
    for (int i = t; i < NBS; i += PT) hs[i] = 0;
    __syncthreads();
    const int beg = blockIdx.x * (EPT * PT);
    int se[EPT], de[EPT];
#pragma unroll
    for (int k = 0; k < EPT; ++k) {
        int e = beg + t + k * PT;
        int s = 0, d = 0;
        if (e < nE) { s = src[e]; d = dst[e]; }   // coalesced
        se[k] = s; de[k] = d;
        if (e < nE) {
            atomicAdd(&hd[d >> 7], 1);
            atomicAdd(&hs[s >> 8], 1);
        }
    }
    __syncthreads();
    for (int i = t; i < NBD; i += PT) { bd[i] = atomicAdd(&dstCur[i], hd[i]); hd[i] = 0; }
    for (int i = t; i < NBS; i += PT) { bs[i] = atomicAdd(&srcCur[i], hs[i]); hs[i] = 0; }
    __syncthreads();
#pragma unroll
    for (int k = 0; k < EPT; ++k) {
        int e = beg + t + k * PT;
        if (e < nE) {
            int d = de[k], s = se[k];
            int b = d >> 7;
            int p = bd[b] + atomicAdd(&hd[b], 1);
            if (p < DB_CAP)
                dstrec[(size_t)b * DB_CAP + p] = ((uint)(d & 127) << 17) | (uint)s;  // s < 2^17
            int b2 = s >> 8;
            int p2 = bs[b2] + atomicAdd(&hs[b2], 1);
            if (p2 < SB_CAP)
                srcrec[(size_t)b2 * SB_CAP + p2] = (ushort)(s & 255);
        }
    }
}

// ========== pass 2: src-degree histogram + prescale (fused) ================
// One block per 256-node src bucket: LDS histogram from srcrec, then emit
// xb[row] = bf16(rsqrt(deg_out)*feat[row]); pad row n = zeros. deg_out
// never touches global memory.
__global__ __launch_bounds__(512) void
prescale_kernel(const ushort* __restrict__ srcrec, const int* __restrict__ srcCur,
                const float* __restrict__ feat, uint2* __restrict__ xb, int n) {
    __shared__ int lc[256];
    const int t = threadIdx.x;
    const int b = blockIdx.x;
    const int base = b << 8;
    if (t < 256) lc[t] = 0;
    __syncthreads();
    int cnt = min(srcCur[b], SB_CAP);
    const ushort* rec = srcrec + (size_t)b * SB_CAP;
    for (int i = t; i < cnt; i += 512) atomicAdd(&lc[rec[i]], 1);
    __syncthreads();
    const int rows = min(256, n + 1 - base);      // includes pad row n; <=0 past it
    const int d4 = t & 15;
    for (int r = t >> 4; r < rows; r += 32) {     // 32 rows/iter, coalesced 1KB/wave
        const int row = base + r;
        uint2 o;
        if (row == n) {
            o.x = 0u; o.y = 0u;
        } else {
            float w = rsqrtf((float)max(lc[r], 1));
            float4 v = ((const float4*)feat)[(size_t)row * 16 + d4];
            o.x = f2bf(w * v.x) | (f2bf(w * v.y) << 16);
            o.y = f2bf(w * v.z) | (f2bf(w * v.w) << 16);
        }
        xb[(size_t)row * 16 + d4] = o;
    }
}

// ========== pass 3: fused bin + gather, one block per 128-node dst bucket ==
// Phase A: LDS histogram of the bucket's records -> wave-0 shfl exclusive
//   scan -> LDS-CSR placement (all atomics LDS-local).  No edge_src/cursor
//   global round-trip, no CAP truncation.
// Phase B: 8 waves gather 16 interleaved rows each, reading edge indices by
//   LDS broadcast (replaces the old shfl machinery) and xb rows (128B lines).
__global__ __launch_bounds__(512) void
binGather_kernel(const uint* __restrict__ dstrec, const int* __restrict__ dstCur,
                 const uint2* __restrict__ xb, float* __restrict__ out, int n) {
    __shared__ int cnt[128], off[128];
    __shared__ int eLDS[DB_CAP];                       // 12 KB
    const int t = threadIdx.x;
    const int b = blockIdx.x;
    const int base = b << 7;
    if (t < 128) cnt[t] = 0;
    __syncthreads();
    const int nr = min(dstCur[b], DB_CAP);
    const uint* rec = dstrec + (size_t)b * DB_CAP;
    for (int i = t; i < nr; i += 512) atomicAdd(&cnt[rec[i] >> 17], 1);
    __syncthreads();
    if (t < 64) {                                      // wave-0 exclusive scan of cnt[0..127]
        int v0 = cnt[t], v1 = cnt[64 + t];
        int s0 = v0, s1 = v1;
        for (int d = 1; d < 64; d <<= 1) {
            int u0 = __shfl_up(s0, d, 64);
            int u1 = __shfl_up(s1, d, 64);
            if (t >= d) { s0 += u0; s1 += u1; }
        }
        int tot0 = __shfl(s0, 63, 64);
        off[t]      = s0 - v0;
        off[64 + t] = tot0 + s1 - v1;
    }
    __syncthreads();
    for (int i = t; i < nr; i += 512) {                // CSR placement
        uint r = rec[i];
        int p = atomicAdd(&off[r >> 17], 1);           // off becomes end-pointer
        eLDS[p] = (int)(r & 0x1FFFF);
    }
    __syncthreads();
    // gather: 8 waves x 16 interleaved rows
    const int wv = t >> 6, lane = t & 63, sub = lane >> 4, d4 = lane & 15;
    for (int k = 0; k < 16; ++k) {
        const int r = wv + (k << 3);                   // wave-uniform
        const int row = base + r;
        if (row >= n) continue;
        const int c = cnt[r];
        const int start = off[r] - c;                  // off[r] = start + c after placement
        float4 acc = {0.f, 0.f, 0.f, 0.f};
        int i = sub;
        for (; i + 4 < c; i += 8) {                    // 2 loads in flight
            int s0 = eLDS[start + i];                  // 16-lane LDS broadcast
            int s1 = eLDS[start + i + 4];
            uint2 v0 = xb[(size_t)s0 * 16 + d4];
            uint2 v1 = xb[(size_t)s1 * 16 + d4];
            acc.x += __uint_as_float(v0.x << 16);
            acc.y += __uint_as_float(v0.x & 0xffff0000u);
            acc.z += __uint_as_float(v0.y << 16);
            acc.w += __uint_as_float(v0.y & 0xffff0000u);
            acc.x += __uint_as_float(v1.x << 16);
            acc.y += __uint_as_float(v1.x & 0xffff0000u);
            acc.z += __uint_as_float(v1.y << 16);
            acc.w += __uint_as_float(v1.y & 0xffff0000u);
        }
        if (i < c) {
            int s0 = eLDS[start + i];
            uint2 v0 = xb[(size_t)s0 * 16 + d4];
            acc.x += __uint_as_float(v0.x << 16);
            acc.y += __uint_as_float(v0.x & 0xffff0000u);
            acc.z += __uint_as_float(v0.y << 16);
            acc.w += __uint_as_float(v0.y & 0xffff0000u);
        }
        for (int o = 16; o < 64; o <<= 1) {            // reduce across 4 subs
            acc.x += __shfl_xor(acc.x, o, 64);
            acc.y += __shfl_xor(acc.y, o, 64);
            acc.z += __shfl_xor(acc.z, o, 64);
            acc.w += __shfl_xor(acc.w, o, 64);
        }
        if (sub == 0) {
            float si = rsqrtf((float)max(c, 1));       // rs_in
            float4 rr = { acc.x * si, acc.y * si, acc.z * si, acc.w * si };
            ((float4*)out)[(size_t)row * 16 + d4] = rr;
        }
    }
}

// ========== fallback: R8's proven single-pass fp32 path ====================
__global__ void bucket_kernel(const int* __restrict__ src, const int* __restrict__ dst,
                              int* __restrict__ cursor, int* __restrict__ deg_out,
                              int* __restrict__ edge_src, int nE) {
    int e = blockIdx.x * blockDim.x + threadIdx.x;
    if (e < nE) {
        int s = src[e];
        int d = dst[e];
        atomicAdd(&deg_out[s], 1);
        int pos = atomicAdd(&cursor[d], 1);
        if (pos < CAP) edge_src[(size_t)d * CAP + pos] = s;
    }
}

__global__ void gather_cap_kernel(const float* __restrict__ feat,
                                  const int* __restrict__ edge_src,
                                  const int* __restrict__ cursor,
                                  const int* __restrict__ deg_out,
                                  float* __restrict__ out, int n) {
    int wave = (blockIdx.x * blockDim.x + threadIdx.x) >> 6;
    if (wave >= n) return;
    int lane = threadIdx.x & 63;
    int cnt = min(cursor[wave], CAP);

    int   s_l = (lane < cnt) ? edge_src[(size_t)wave * CAP + lane] : 0;
    float w_l = (lane < cnt) ? rsqrtf((float)max(deg_out[s_l], 1)) : 0.0f;

    int sub = lane >> 4;
    int d4  = lane & 15;
    float4 a0 = {0.f,0.f,0.f,0.f}, a1 = {0.f,0.f,0.f,0.f};

    for (int i = 0; i < cnt; i += 8) {
        int   s0 = __shfl(s_l, i + sub, 64);
        float w0 = __shfl(w_l, i + sub, 64);
        int   s1 = __shfl(s_l, i + sub + 4, 64);
        float w1 = __shfl(w_l, i + sub + 4, 64);
        float4 v0 = ((const float4*)feat)[(size_t)s0 * 16 + d4];
        float4 v1 = ((const float4*)feat)[(size_t)s1 * 16 + d4];
        a0.x += w0 * v0.x; a0.y += w0 * v0.y; a0.z += w0 * v0.z; a0.w += w0 * v0.w;
        a1.x += w1 * v1.x; a1.y += w1 * v1.y; a1.z += w1 * v1.z; a1.w += w1 * v1.w;
    }
    float4 acc = { a0.x + a1.x, a0.y + a1.y, a0.z + a1.z, a0.w + a1.w };
    for (int off = 16; off < 64; off <<= 1) {
        acc.x += __shfl_xor(acc.x, off, 64);
        acc.y += __shfl_xor(acc.y, off, 64);
        acc.z += __shfl_xor(acc.z, off, 64);
        acc.w += __shfl_xor(acc.w, off, 64);
    }
    if (sub == 0) {
        float si = rsqrtf((float)max(cnt, 1));
        float4 r = { acc.x * si, acc.y * si, acc.z * si, acc.w * si };
        ((float4*)out)[(size_t)wave * 16 + d4] = r;
    }
}

// ===========================================================================

extern "C" void kernel_launch(void* const* d_in, const int* in_sizes, int n_in,
                              void* d_out, int out_size, void* d_ws, size_t ws_size,
                              hipStream_t stream) {
    const float* feat = (const float*)d_in[0];
    const int*   src  = (const int*)d_in[1];
    const int*   dst  = (const int*)d_in[2];
    float* out = (float*)d_out;
    const int nE = in_sizes[1];
    const int n  = N_NODES;

    // Fast-path layout (512-B aligned sections; xb rows must not straddle
    // cache lines -- round 1 proved a 96-mod-128 xb offset costs ~14 us):
    //   dstCur[NBD] srcCur[NBS] | dstrec | srcrec | xb
    // No cursor / deg_out / edge_src on this path anymore.
    const size_t ctr_bytes = (NBD + NBS) * sizeof(int);               // 4704
    const size_t dr_off    = (ctr_bytes + 511) & ~(size_t)511;        // 4736 -> 5120? (aligned)
    const size_t dr_sz     = (size_t)NBD * DB_CAP * sizeof(uint);     // 9,633,792
    const size_t sr_off    = dr_off + dr_sz;                          // 512-mult
    const size_t sr_sz     = (size_t)NBS * SB_CAP * sizeof(ushort);   // 4,312,000
    const size_t xb_off    = (sr_off + sr_sz + 511) & ~(size_t)511;
    const size_t xb_bytes  = (size_t)(n + 1) * 16 * sizeof(uint2);    // 12,800,128
    const size_t need_new  = xb_off + xb_bytes;                       // ~26.8 MB
    const size_t need_fp   = (size_t)n * (2 + CAP) * sizeof(int);     // ~26.4 MB

    if (ws_size >= need_new) {
        char*   W        = (char*)d_ws;
        int*    dstCur   = (int*)W;
        int*    srcCur   = dstCur + NBD;
        uint*   dstrec   = (uint*)(W + dr_off);
        ushort* srcrec   = (ushort*)(W + sr_off);
        uint2*  xb       = (uint2*)(W + xb_off);

        hipMemsetAsync(dstCur, 0, ctr_bytes, stream);
        {
            const int chunk = EPT * PT;                       // 3584
            const int grid = (nE + chunk - 1) / chunk;        // 475 for 1.7M edges
            partition_kernel<<<grid, PT, 0, stream>>>(src, dst, dstCur, srcCur,
                                                      dstrec, srcrec, nE);
        }
        prescale_kernel<<<NBS, 512, 0, stream>>>(srcrec, srcCur, feat, xb, n);
        binGather_kernel<<<NBD, 512, 0, stream>>>(dstrec, dstCur, xb, out, n);
    } else if (ws_size >= need_fp) {
        // R8's proven fp32 path: cursor[n] | deg_out[n] | edge_src[n*CAP]
        int* cursor   = (int*)d_ws;
        int* deg_out  = cursor + n;
        int* edge_src = deg_out + n;

        hipMemsetAsync(cursor, 0, 2 * (size_t)n * sizeof(int), stream);
        {
            int block = 256, grid = (nE + block - 1) / block;
            bucket_kernel<<<grid, block, 0, stream>>>(src, dst, cursor, deg_out, edge_src, nE);
        }
        {
            int block = 256, grid = (n + 3) / 4;
            gather_cap_kernel<<<grid, block, 0, stream>>>(feat, edge_src, cursor, deg_out, out, n);
        }
    }
}

// Round 6
// 162.167 us; speedup vs baseline: 1.3433x; 1.0123x over previous
//
#include <hip/hip_runtime.h>
#include <hip/hip_bf16.h>

#define N_NODES 100000
#define D_FEAT 64
#define CAP 64          // fallback path only
#define NBD 784         // dst buckets of 128 nodes: 784*128 = 100352 >= n
#define DB_CAP 3072     // per-dst-bucket record cap (mean 2176, +19 sigma) == LDS CSR cap
#define NBS 392         // src buckets of 256 nodes: 392*256 = 100352 >= n+1
#define SB_CAP 5500     // per-src-bucket record cap (mean 4336, +17 sigma)
#define PT 512          // partition threads per block
#define EPT 7           // edges register-cached per thread; chunk = EPT*PT = 3584

typedef unsigned int uint;
typedef unsigned short ushort;

// fp32 -> bf16 round-to-nearest-even
__device__ __forceinline__ uint f2bf(float f) {
    uint u = __float_as_uint(f);
    return (u + 0x7fffu + ((u >> 16) & 1u)) >> 16;
}

// ========== pass 1: coarse partition (dst>>7 records, src>>8 records) ======
// Rank-capture two-phase: the phase-1 histogram atomicAdd RETURNS each
// edge's within-(block,bucket) rank -- keep it in registers, so phase 3 is
// pure stores at bd[b]+rank.  2 LDS atomics/edge total (was 4), no LDS
// reset, no replay-atomic serialization.  ALL per-edge atomics stay in LDS
// (rounds 2+4 proved per-edge GLOBAL atomics are 2x-worse memory-side RMWs).
__global__ __launch_bounds__(PT) void
partition_kernel(const int* __restrict__ src, const int* __restrict__ dst,
                 int* __restrict__ dstCur, int* __restrict__ srcCur,
                 uint* __restrict__ dstrec, ushort* __restrict__ srcrec,
                 int nE) {
    __shared__ int hd[NBD], bd[NBD], hs[NBS], bs[NBS];
    const int t = threadIdx.x;
    for (int i = t; i < NBD; i += PT) hd[i] = 0;
    for (int i = t; i < NBS; i += PT) hs[i] = 0;
    __syncthreads();
    const int beg = blockIdx.x * (EPT * PT);
    int se[EPT], de[EPT], rd[EPT], rs[EPT];
#pragma unroll
    for (int k = 0; k < EPT; ++k) {
        int e = beg + t + k * PT;
        int s = 0, d = 0, r1 = 0, r2 = 0;
        if (e < nE) {
            s = src[e]; d = dst[e];                // coalesced
            r1 = atomicAdd(&hd[d >> 7], 1);        // rank within (block, dst-bucket)
            r2 = atomicAdd(&hs[s >> 8], 1);        // rank within (block, src-bucket)
        }
        se[k] = s; de[k] = d; rd[k] = r1; rs[k] = r2;
    }
    __syncthreads();
    for (int i = t; i < NBD; i += PT) bd[i] = atomicAdd(&dstCur[i], hd[i]);
    for (int i = t; i < NBS; i += PT) bs[i] = atomicAdd(&srcCur[i], hs[i]);
    __syncthreads();
#pragma unroll
    for (int k = 0; k < EPT; ++k) {
        int e = beg + t + k * PT;
        if (e < nE) {
            int d = de[k], s = se[k];
            int p = bd[d >> 7] + rd[k];            // no atomic: rank captured in phase 1
            if (p < DB_CAP)
                dstrec[(size_t)(d >> 7) * DB_CAP + p] = ((uint)(d & 127) << 17) | (uint)s;  // s < 2^17
            int p2 = bs[s >> 8] + rs[k];
            if (p2 < SB_CAP)
                srcrec[(size_t)(s >> 8) * SB_CAP + p2] = (ushort)(s & 255);
        }
    }
}

// ========== pass 2: src-degree histogram + prescale (fused) ================
// One block per 256-node src bucket: LDS histogram from srcrec (paired uint
// reads, 2 records/load), then emit xb[row] = bf16(rsqrt(deg_out)*feat[row]);
// pad row n = zeros.  deg_out never touches global memory.
__global__ __launch_bounds__(512) void
prescale_kernel(const ushort* __restrict__ srcrec, const int* __restrict__ srcCur,
                const float* __restrict__ feat, uint2* __restrict__ xb, int n) {
    __shared__ int lc[256];
    const int t = threadIdx.x;
    const int b = blockIdx.x;
    const int base = b << 8;
    if (t < 256) lc[t] = 0;
    __syncthreads();
    int cnt = min(srcCur[b], SB_CAP);
    const uint* rec2 = (const uint*)(srcrec + (size_t)b * SB_CAP);  // SB_CAP even -> aligned
    const int pairs = cnt >> 1;
    for (int i = t; i < pairs; i += 512) {
        uint rr = rec2[i];
        atomicAdd(&lc[rr & 0xFFu], 1);
        atomicAdd(&lc[(rr >> 16) & 0xFFu], 1);
    }
    if ((cnt & 1) && t == 0)
        atomicAdd(&lc[srcrec[(size_t)b * SB_CAP + cnt - 1]], 1);
    __syncthreads();
    const int rows = min(256, n + 1 - base);      // includes pad row n; <=0 past it
    const int d4 = t & 15;
    for (int r = t >> 4; r < rows; r += 32) {     // 32 rows/iter, coalesced 1KB/wave
        const int row = base + r;
        uint2 o;
        if (row == n) {
            o.x = 0u; o.y = 0u;
        } else {
            float w = rsqrtf((float)max(lc[r], 1));
            float4 v = ((const float4*)feat)[(size_t)row * 16 + d4];
            o.x = f2bf(w * v.x) | (f2bf(w * v.y) << 16);
            o.y = f2bf(w * v.z) | (f2bf(w * v.w) << 16);
        }
        xb[(size_t)row * 16 + d4] = o;
    }
}

// ========== pass 3: fused bin + gather, one block per 128-node dst bucket ==
// (proven round-5 structure, unchanged)
// Phase A: LDS histogram -> wave-0 shfl scan -> LDS-CSR placement.
// Phase B: 8 waves gather 16 interleaved rows each, edge indices via LDS
//   broadcast, xb rows as 128-B lines.
__global__ __launch_bounds__(512) void
binGather_kernel(const uint* __restrict__ dstrec, const int* __restrict__ dstCur,
                 const uint2* __restrict__ xb, float* __restrict__ out, int n) {
    __shared__ int cnt[128], off[128];
    __shared__ int eLDS[DB_CAP];                       // 12 KB
    const int t = threadIdx.x;
    const int b = blockIdx.x;
    const int base = b << 7;
    if (t < 128) cnt[t] = 0;
    __syncthreads();
    const int nr = min(dstCur[b], DB_CAP);
    const uint* rec = dstrec + (size_t)b * DB_CAP;
    for (int i = t; i < nr; i += 512) atomicAdd(&cnt[rec[i] >> 17], 1);
    __syncthreads();
    if (t < 64) {                                      // wave-0 exclusive scan of cnt[0..127]
        int v0 = cnt[t], v1 = cnt[64 + t];
        int s0 = v0, s1 = v1;
        for (int d = 1; d < 64; d <<= 1) {
            int u0 = __shfl_up(s0, d, 64);
            int u1 = __shfl_up(s1, d, 64);
            if (t >= d) { s0 += u0; s1 += u1; }
        }
        int tot0 = __shfl(s0, 63, 64);
        off[t]      = s0 - v0;
        off[64 + t] = tot0 + s1 - v1;
    }
    __syncthreads();
    for (int i = t; i < nr; i += 512) {                // CSR placement
        uint r = rec[i];
        int p = atomicAdd(&off[r >> 17], 1);           // off becomes end-pointer
        eLDS[p] = (int)(r & 0x1FFFF);
    }
    __syncthreads();
    // gather: 8 waves x 16 interleaved rows
    const int wv = t >> 6, lane = t & 63, sub = lane >> 4, d4 = lane & 15;
    for (int k = 0; k < 16; ++k) {
        const int r = wv + (k << 3);                   // wave-uniform
        const int row = base + r;
        if (row >= n) continue;
        const int c = cnt[r];
        const int start = off[r] - c;                  // off[r] = start + c after placement
        float4 acc = {0.f, 0.f, 0.f, 0.f};
        int i = sub;
        for (; i + 4 < c; i += 8) {                    // 2 loads in flight
            int s0 = eLDS[start + i];                  // 16-lane LDS broadcast
            int s1 = eLDS[start + i + 4];
            uint2 v0 = xb[(size_t)s0 * 16 + d4];
            uint2 v1 = xb[(size_t)s1 * 16 + d4];
            acc.x += __uint_as_float(v0.x << 16);
            acc.y += __uint_as_float(v0.x & 0xffff0000u);
            acc.z += __uint_as_float(v0.y << 16);
            acc.w += __uint_as_float(v0.y & 0xffff0000u);
            acc.x += __uint_as_float(v1.x << 16);
            acc.y += __uint_as_float(v1.x & 0xffff0000u);
            acc.z += __uint_as_float(v1.y << 16);
            acc.w += __uint_as_float(v1.y & 0xffff0000u);
        }
        if (i < c) {
            int s0 = eLDS[start + i];
            uint2 v0 = xb[(size_t)s0 * 16 + d4];
            acc.x += __uint_as_float(v0.x << 16);
            acc.y += __uint_as_float(v0.x & 0xffff0000u);
            acc.z += __uint_as_float(v0.y << 16);
            acc.w += __uint_as_float(v0.y & 0xffff0000u);
        }
        for (int o = 16; o < 64; o <<= 1) {            // reduce across 4 subs
            acc.x += __shfl_xor(acc.x, o, 64);
            acc.y += __shfl_xor(acc.y, o, 64);
            acc.z += __shfl_xor(acc.z, o, 64);
            acc.w += __shfl_xor(acc.w, o, 64);
        }
        if (sub == 0) {
            float si = rsqrtf((float)max(c, 1));       // rs_in
            float4 rr = { acc.x * si, acc.y * si, acc.z * si, acc.w * si };
            ((float4*)out)[(size_t)row * 16 + d4] = rr;
        }
    }
}

// ========== fallback: R8's proven single-pass fp32 path ====================
__global__ void bucket_kernel(const int* __restrict__ src, const int* __restrict__ dst,
                              int* __restrict__ cursor, int* __restrict__ deg_out,
                              int* __restrict__ edge_src, int nE) {
    int e = blockIdx.x * blockDim.x + threadIdx.x;
    if (e < nE) {
        int s = src[e];
        int d = dst[e];
        atomicAdd(&deg_out[s], 1);
        int pos = atomicAdd(&cursor[d], 1);
        if (pos < CAP) edge_src[(size_t)d * CAP + pos] = s;
    }
}

__global__ void gather_cap_kernel(const float* __restrict__ feat,
                                  const int* __restrict__ edge_src,
                                  const int* __restrict__ cursor,
                                  const int* __restrict__ deg_out,
                                  float* __restrict__ out, int n) {
    int wave = (blockIdx.x * blockDim.x + threadIdx.x) >> 6;
    if (wave >= n) return;
    int lane = threadIdx.x & 63;
    int cnt = min(cursor[wave], CAP);

    int   s_l = (lane < cnt) ? edge_src[(size_t)wave * CAP + lane] : 0;
    float w_l = (lane < cnt) ? rsqrtf((float)max(deg_out[s_l], 1)) : 0.0f;

    int sub = lane >> 4;
    int d4  = lane & 15;
    float4 a0 = {0.f,0.f,0.f,0.f}, a1 = {0.f,0.f,0.f,0.f};

    for (int i = 0; i < cnt; i += 8) {
        int   s0 = __shfl(s_l, i + sub, 64);
        float w0 = __shfl(w_l, i + sub, 64);
        int   s1 = __shfl(s_l, i + sub + 4, 64);
        float w1 = __shfl(w_l, i + sub + 4, 64);
        float4 v0 = ((const float4*)feat)[(size_t)s0 * 16 + d4];
        float4 v1 = ((const float4*)feat)[(size_t)s1 * 16 + d4];
        a0.x += w0 * v0.x; a0.y += w0 * v0.y; a0.z += w0 * v0.z; a0.w += w0 * v0.w;
        a1.x += w1 * v1.x; a1.y += w1 * v1.y; a1.z += w1 * v1.z; a1.w += w1 * v1.w;
    }
    float4 acc = { a0.x + a1.x, a0.y + a1.y, a0.z + a1.z, a0.w + a1.w };
    for (int off = 16; off < 64; off <<= 1) {
        acc.x += __shfl_xor(acc.x, off, 64);
        acc.y += __shfl_xor(acc.y, off, 64);
        acc.z += __shfl_xor(acc.z, off, 64);
        acc.w += __shfl_xor(acc.w, off, 64);
    }
    if (sub == 0) {
        float si = rsqrtf((float)max(cnt, 1));
        float4 r = { acc.x * si, acc.y * si, acc.z * si, acc.w * si };
        ((float4*)out)[(size_t)wave * 16 + d4] = r;
    }
}

// ===========================================================================

extern "C" void kernel_launch(void* const* d_in, const int* in_sizes, int n_in,
                              void* d_out, int out_size, void* d_ws, size_t ws_size,
                              hipStream_t stream) {
    const float* feat = (const float*)d_in[0];
    const int*   src  = (const int*)d_in[1];
    const int*   dst  = (const int*)d_in[2];
    float* out = (float*)d_out;
    const int nE = in_sizes[1];
    const int n  = N_NODES;

    // Fast-path layout (512-B aligned sections; xb rows must not straddle
    // cache lines -- round 1 proved a 96-mod-128 xb offset costs ~14 us):
    //   dstCur[NBD] srcCur[NBS] | dstrec | srcrec | xb
    const size_t ctr_bytes = (NBD + NBS) * sizeof(int);               // 4704
    const size_t dr_off    = (ctr_bytes + 511) & ~(size_t)511;
    const size_t dr_sz     = (size_t)NBD * DB_CAP * sizeof(uint);     // 9,633,792
    const size_t sr_off    = dr_off + dr_sz;                          // 512-mult
    const size_t sr_sz     = (size_t)NBS * SB_CAP * sizeof(ushort);   // 4,312,000
    const size_t xb_off    = (sr_off + sr_sz + 511) & ~(size_t)511;
    const size_t xb_bytes  = (size_t)(n + 1) * 16 * sizeof(uint2);    // 12,800,128
    const size_t need_new  = xb_off + xb_bytes;                       // ~26.8 MB
    const size_t need_fp   = (size_t)n * (2 + CAP) * sizeof(int);     // ~26.4 MB

    if (ws_size >= need_new) {
        char*   W        = (char*)d_ws;
        int*    dstCur   = (int*)W;
        int*    srcCur   = dstCur + NBD;
        uint*   dstrec   = (uint*)(W + dr_off);
        ushort* srcrec   = (ushort*)(W + sr_off);
        uint2*  xb       = (uint2*)(W + xb_off);

        hipMemsetAsync(dstCur, 0, ctr_bytes, stream);
        {
            const int chunk = EPT * PT;                       // 3584
            const int grid = (nE + chunk - 1) / chunk;        // 475 for 1.7M edges
            partition_kernel<<<grid, PT, 0, stream>>>(src, dst, dstCur, srcCur,
                                                      dstrec, srcrec, nE);
        }
        prescale_kernel<<<NBS, 512, 0, stream>>>(srcrec, srcCur, feat, xb, n);
        binGather_kernel<<<NBD, 512, 0, stream>>>(dstrec, dstCur, xb, out, n);
    } else if (ws_size >= need_fp) {
        // R8's proven fp32 path: cursor[n] | deg_out[n] | edge_src[n*CAP]
        int* cursor   = (int*)d_ws;
        int* deg_out  = cursor + n;
        int* edge_src = deg_out + n;

        hipMemsetAsync(cursor, 0, 2 * (size_t)n * sizeof(int), stream);
        {
            int block = 256, grid = (nE + block - 1) / block;
            bucket_kernel<<<grid, block, 0, stream>>>(src, dst, cursor, deg_out, edge_src, nE);
        }
        {
            int block = 256, grid = (n + 3) / 4;
            gather_cap_kernel<<<grid, block, 0, stream>>>(feat, edge_src, cursor, deg_out, out, n);
        }
    }
}